// Round 2
// baseline (139.929 us; speedup 1.0000x reference)
//
#include <hip/hip_runtime.h>
#include <math.h>

// Problem constants (match reference)
#define B_ 2
#define T_ 2048
#define M_ 768
#define R_ 64
#define S_ 16
#define MS_ (M_ * S_)
#define LOG_EPS_F (-23.025850929940457f)

// --------------------------------------------------------------------------
// Kernel 1: dt[bt][m] = clip(softplus(delta[bt][:] . dt_w[m][:] + dt_b[m]))
// Tiled 64x64 GEMM-like, K=64, LDS-staged with transpose.
// --------------------------------------------------------------------------
__global__ __launch_bounds__(256) void dt_kernel(
    const float* __restrict__ delta,   // [B*T][R]
    const float* __restrict__ dt_w,    // [M][R]
    const float* __restrict__ dt_b,    // [M]
    float* __restrict__ dt_out)        // [B*T][M]
{
  __shared__ float ds_d[R_][68];
  __shared__ float ds_w[R_][68];
  const int tid = threadIdx.x;
  const int m0  = blockIdx.x * 64;
  const int bt0 = blockIdx.y * 64;

  #pragma unroll
  for (int k = 0; k < 4; ++k) {
    int idx = tid + k * 256;
    int rq = idx & 15;
    int x  = idx >> 4;
    float4 dv = *reinterpret_cast<const float4*>(&delta[(size_t)(bt0 + x) * R_ + rq * 4]);
    ds_d[rq * 4 + 0][x] = dv.x; ds_d[rq * 4 + 1][x] = dv.y;
    ds_d[rq * 4 + 2][x] = dv.z; ds_d[rq * 4 + 3][x] = dv.w;
    float4 wv = *reinterpret_cast<const float4*>(&dt_w[(size_t)(m0 + x) * R_ + rq * 4]);
    ds_w[rq * 4 + 0][x] = wv.x; ds_w[rq * 4 + 1][x] = wv.y;
    ds_w[rq * 4 + 2][x] = wv.z; ds_w[rq * 4 + 3][x] = wv.w;
  }
  __syncthreads();

  const int mq = tid & 15, tq = tid >> 4;
  const int ml = mq * 4, tl = tq * 4;
  float acc[4][4] = {};
  #pragma unroll 4
  for (int r = 0; r < R_; ++r) {
    float4 dv = *reinterpret_cast<const float4*>(&ds_d[r][tl]);
    float4 wv = *reinterpret_cast<const float4*>(&ds_w[r][ml]);
    float d[4] = {dv.x, dv.y, dv.z, dv.w};
    float w[4] = {wv.x, wv.y, wv.z, wv.w};
    #pragma unroll
    for (int i = 0; i < 4; ++i)
      #pragma unroll
      for (int j = 0; j < 4; ++j)
        acc[i][j] = fmaf(d[i], w[j], acc[i][j]);
  }

  float4 bb = *reinterpret_cast<const float4*>(&dt_b[m0 + ml]);
  float bv[4] = {bb.x, bb.y, bb.z, bb.w};
  #pragma unroll
  for (int i = 0; i < 4; ++i) {
    float4 o;
    float* op = &o.x;
    #pragma unroll
    for (int j = 0; j < 4; ++j) {
      float x = acc[i][j] + bv[j];
      float sp = (x > 20.f) ? x : log1pf(__expf(x));
      op[j] = fminf(fmaxf(sp, 1e-6f), 10.f);
    }
    *reinterpret_cast<float4*>(&dt_out[(size_t)(bt0 + tl + i) * M_ + m0 + ml]) = o;
  }
}

// --------------------------------------------------------------------------
// Kernel 2 (v2): W = [B_w; C_w] (32x768) staged in LDS (96 KB). 512 threads,
// 8 waves; each wave computes 2 bt rows. Coalesced float4 u loads,
// conflict-free ds_read_b128 W reads, butterfly cross-lane reduction.
// --------------------------------------------------------------------------
__global__ __launch_bounds__(512) void bc_kernel(
    const float* __restrict__ u,     // [B*T][M]
    const float* __restrict__ B_w,   // [S][M]
    const float* __restrict__ C_w,   // [S][M]
    float* __restrict__ Bm,          // [B*T][S]
    float* __restrict__ Cm)          // [B*T][S]
{
  __shared__ float w_lds[32][M_];
  const int tid = threadIdx.x;

  #pragma unroll
  for (int k = 0; k < 12; ++k) {
    int i4 = tid + k * 512;                 // 0..6143 (float4 index)
    int row = i4 / 192;                     // 0..31
    int col4 = i4 - row * 192;
    const float* src = (row < 16) ? &B_w[(size_t)row * M_] : &C_w[(size_t)(row - 16) * M_];
    float4 v = *reinterpret_cast<const float4*>(&src[col4 * 4]);
    *reinterpret_cast<float4*>(&w_lds[row][col4 * 4]) = v;
  }
  __syncthreads();

  const int wave = tid >> 6, lane = tid & 63;
  const int bt0 = blockIdx.x * 16 + wave * 2;
  const float4* u0 = reinterpret_cast<const float4*>(&u[(size_t)bt0 * M_]);
  const float4* u1 = reinterpret_cast<const float4*>(&u[(size_t)(bt0 + 1) * M_]);

  float acc0[32], acc1[32];
  #pragma unroll
  for (int s = 0; s < 32; ++s) { acc0[s] = 0.f; acc1[s] = 0.f; }

  #pragma unroll
  for (int it = 0; it < 3; ++it) {
    float4 a  = u0[it * 64 + lane];
    float4 bq = u1[it * 64 + lane];
    const int mb = it * 256 + lane * 4;
    #pragma unroll
    for (int s = 0; s < 32; ++s) {
      float4 wv = *reinterpret_cast<const float4*>(&w_lds[s][mb]);
      acc0[s] = fmaf(a.x,  wv.x, acc0[s]); acc0[s] = fmaf(a.y,  wv.y, acc0[s]);
      acc0[s] = fmaf(a.z,  wv.z, acc0[s]); acc0[s] = fmaf(a.w,  wv.w, acc0[s]);
      acc1[s] = fmaf(bq.x, wv.x, acc1[s]); acc1[s] = fmaf(bq.y, wv.y, acc1[s]);
      acc1[s] = fmaf(bq.z, wv.z, acc1[s]); acc1[s] = fmaf(bq.w, wv.w, acc1[s]);
    }
  }

  // cross-lane reduce: 64 lanes x 32 partials -> lane i holds full sum for s=i&31
  #pragma unroll
  for (int j = 0; j < 32; ++j) {
    acc0[j] += __shfl_xor(acc0[j], 32);
    acc1[j] += __shfl_xor(acc1[j], 32);
  }
  int cnt = 32;
  #pragma unroll
  for (int mask = 16; mask >= 1; mask >>= 1) {
    cnt >>= 1;
    const bool up = (lane & mask) != 0;
    #pragma unroll
    for (int j = 0; j < cnt; ++j) {
      float give0 = up ? acc0[j] : acc0[j + cnt];
      float keep0 = up ? acc0[j + cnt] : acc0[j];
      acc0[j] = keep0 + __shfl_xor(give0, mask);
      float give1 = up ? acc1[j] : acc1[j + cnt];
      float keep1 = up ? acc1[j + cnt] : acc1[j];
      acc1[j] = keep1 + __shfl_xor(give1, mask);
    }
  }

  if (lane < 32) {
    const int s = lane;
    if (s < 16) {
      Bm[(size_t)bt0 * S_ + s] = acc0[0];
      Bm[(size_t)(bt0 + 1) * S_ + s] = acc1[0];
    } else {
      Cm[(size_t)bt0 * S_ + (s - 16)] = acc0[0];
      Cm[(size_t)(bt0 + 1) * S_ + (s - 16)] = acc1[0];
    }
  }
}

// --------------------------------------------------------------------------
// Kernels 3 & 5: chunk-local scan. Thread owns (b, m, chunk), 16 s-states in
// registers. dt/u chunk preloaded to regs; Bm/Cm chunk staged in LDS.
// --------------------------------------------------------------------------
template <int PHASE, int NCt>
__global__ __launch_bounds__(256) void scan_kernel(
    const float* __restrict__ dt_ws,   // [B*T][M]
    const float* __restrict__ u,       // [B*T][M]
    const float* __restrict__ Bm,      // [B*T][S]
    const float* __restrict__ Cm,      // [B*T][S]
    const float* __restrict__ A_log,   // [S][M]
    const float* __restrict__ D,       // [M]
    float* __restrict__ Aprod,         // [B][NCt][M][S]
    float* __restrict__ Hend,          // [B][NCt][M][S]
    const float* __restrict__ carry,   // [B][NCt][M][S]
    float* __restrict__ out)           // [B*T][M]
{
  constexpr int CL = T_ / NCt;
  __shared__ float lds_bm[CL * S_];
  __shared__ float lds_cm[CL * S_];
  const int tid = threadIdx.x;
  const int m = blockIdx.x * 256 + tid;
  const int c = blockIdx.y;
  const int b = blockIdx.z;
  const int t0 = c * CL;

  for (int idx = tid; idx < CL * S_; idx += 256) {
    lds_bm[idx] = Bm[((size_t)b * T_ + t0) * S_ + idx];
    if constexpr (PHASE == 3) lds_cm[idx] = Cm[((size_t)b * T_ + t0) * S_ + idx];
  }
  __syncthreads();

  float Acol[S_];
  #pragma unroll
  for (int s = 0; s < S_; ++s) {
    float a = -__expf(A_log[(size_t)s * M_ + m]);
    Acol[s] = fminf(fmaxf(a, -10.f), -1e-6f);
  }

  float h[S_], P[S_];
  float Dm = 0.f;
  if constexpr (PHASE == 1) {
    #pragma unroll
    for (int s = 0; s < S_; ++s) { h[s] = 0.f; P[s] = 1.f; }
  } else {
    const size_t cb = (((size_t)b * NCt + c) * M_ + m) * S_;
    #pragma unroll
    for (int s4 = 0; s4 < 4; ++s4) {
      float4 hv = *reinterpret_cast<const float4*>(&carry[cb + s4 * 4]);
      h[s4 * 4 + 0] = hv.x; h[s4 * 4 + 1] = hv.y;
      h[s4 * 4 + 2] = hv.z; h[s4 * 4 + 3] = hv.w;
    }
    Dm = D[m];
  }

  // preload chunk's dt/u (all loads issued before the serial recurrence)
  float dtc[CL], uc[CL];
  #pragma unroll
  for (int tl = 0; tl < CL; ++tl) {
    const size_t gi = ((size_t)b * T_ + t0 + tl) * M_ + m;
    dtc[tl] = dt_ws[gi];
    uc[tl]  = u[gi];
  }

  #pragma unroll
  for (int tl = 0; tl < CL; ++tl) {
    const float dtv = dtc[tl];
    const float uv  = uc[tl];
    const float du  = dtv * uv;
    float y = 0.f;
    #pragma unroll
    for (int s = 0; s < S_; ++s) {
      float la = fmaxf(dtv * Acol[s], LOG_EPS_F);
      float e = __expf(la);
      h[s] = fmaf(e, h[s], du * lds_bm[tl * S_ + s]);
      if constexpr (PHASE == 1) P[s] *= e;
      else y = fmaf(h[s], lds_cm[tl * S_ + s], y);
    }
    if constexpr (PHASE == 3) {
      float o = y + uv * Dm;
      o = fminf(fmaxf(o, -1e4f), 1e4f);
      out[((size_t)b * T_ + t0 + tl) * M_ + m] = o;
    }
  }

  if constexpr (PHASE == 1) {
    const size_t sb = (((size_t)b * NCt + c) * M_ + m) * S_;
    #pragma unroll
    for (int s4 = 0; s4 < 4; ++s4) {
      float4 pv = make_float4(P[s4 * 4 + 0], P[s4 * 4 + 1], P[s4 * 4 + 2], P[s4 * 4 + 3]);
      *reinterpret_cast<float4*>(&Aprod[sb + s4 * 4]) = pv;
      float4 hv = make_float4(h[s4 * 4 + 0], h[s4 * 4 + 1], h[s4 * 4 + 2], h[s4 * 4 + 3]);
      *reinterpret_cast<float4*>(&Hend[sb + s4 * 4]) = hv;
    }
  }
}

// --------------------------------------------------------------------------
// Kernel 4: combine chunk summaries into per-chunk input carries.
// Coalesced across threads (thread = (b,ms)); unroll pipelines the loads.
// --------------------------------------------------------------------------
template <int NCt>
__global__ __launch_bounds__(256) void carry_kernel(
    const float* __restrict__ Aprod, const float* __restrict__ Hend,
    float* __restrict__ carry)
{
  const int idx = blockIdx.x * 256 + threadIdx.x;  // over B*M*S
  const int b = idx / MS_;
  const int ms = idx - b * MS_;
  float h = 0.f;
  #pragma unroll 16
  for (int c = 0; c < NCt; ++c) {
    const size_t o = ((size_t)b * NCt + c) * MS_ + ms;
    carry[o] = h;
    h = fmaf(Aprod[o], h, Hend[o]);
  }
}

// --------------------------------------------------------------------------
extern "C" void kernel_launch(void* const* d_in, const int* in_sizes, int n_in,
                              void* d_out, int out_size, void* d_ws, size_t ws_size,
                              hipStream_t stream)
{
  const float* u     = (const float*)d_in[0];
  const float* delta = (const float*)d_in[1];
  const float* dt_w  = (const float*)d_in[2];
  const float* dt_b  = (const float*)d_in[3];
  const float* A_log = (const float*)d_in[4];
  const float* B_w   = (const float*)d_in[5];
  const float* C_w   = (const float*)d_in[6];
  const float* D     = (const float*)d_in[7];
  float* out = (float*)d_out;
  float* ws  = (float*)d_ws;

  const size_t fl_dt = (size_t)B_ * T_ * M_;      // 3,145,728
  const size_t fl_bc = (size_t)B_ * T_ * S_;      // 65,536

  // NC=128 needs dt + 2*bc + 3*(B*128*M*S) floats = ~50.9 MB; fall back to
  // NC=64 (~32.0 MB, proven to fit) if the workspace is smaller.
  const size_t sum128 = (size_t)B_ * 128 * MS_;
  const size_t need128 = (fl_dt + 2 * fl_bc + 3 * sum128) * sizeof(float);
  const bool big = ws_size >= need128;

  float* dt_ws = ws;
  float* Bm    = dt_ws + fl_dt;
  float* Cm    = Bm + fl_bc;
  float* Aprod = Cm + fl_bc;

  dt_kernel<<<dim3(M_ / 64, (B_ * T_) / 64), 256, 0, stream>>>(delta, dt_w, dt_b, dt_ws);
  bc_kernel<<<dim3((B_ * T_) / 16), 512, 0, stream>>>(u, B_w, C_w, Bm, Cm);

  if (big) {
    constexpr int NCt = 128;
    const size_t sumN = (size_t)B_ * NCt * MS_;
    float* Hend  = Aprod + sumN;
    float* carry = Hend + sumN;
    scan_kernel<1, NCt><<<dim3(M_ / 256, NCt, B_), 256, 0, stream>>>(
        dt_ws, u, Bm, Cm, A_log, D, Aprod, Hend, nullptr, nullptr);
    carry_kernel<NCt><<<dim3((B_ * MS_) / 256), 256, 0, stream>>>(Aprod, Hend, carry);
    scan_kernel<3, NCt><<<dim3(M_ / 256, NCt, B_), 256, 0, stream>>>(
        dt_ws, u, Bm, Cm, A_log, D, Aprod, Hend, carry, out);
  } else {
    constexpr int NCt = 64;
    const size_t sumN = (size_t)B_ * NCt * MS_;
    float* Hend  = Aprod + sumN;
    float* carry = Hend + sumN;
    scan_kernel<1, NCt><<<dim3(M_ / 256, NCt, B_), 256, 0, stream>>>(
        dt_ws, u, Bm, Cm, A_log, D, Aprod, Hend, nullptr, nullptr);
    carry_kernel<NCt><<<dim3((B_ * MS_) / 256), 256, 0, stream>>>(Aprod, Hend, carry);
    scan_kernel<3, NCt><<<dim3(M_ / 256, NCt, B_), 256, 0, stream>>>(
        dt_ws, u, Bm, Cm, A_log, D, Aprod, Hend, carry, out);
  }
}

// Round 3
// 125.896 us; speedup vs baseline: 1.1115x; 1.1115x over previous
//
#include <hip/hip_runtime.h>
#include <math.h>

// Problem constants (match reference)
#define B_ 2
#define T_ 2048
#define M_ 768
#define R_ 64
#define S_ 16
#define MS_ (M_ * S_)
#define LOG_EPS_F (-23.025850929940457f)

// --------------------------------------------------------------------------
// Kernel 1: dt[bt][m] = clip(softplus(delta[bt][:] . dt_w[m][:] + dt_b[m]))
// Tiled 64x64 GEMM-like, K=64, LDS-staged with transpose.
// --------------------------------------------------------------------------
__global__ __launch_bounds__(256) void dt_kernel(
    const float* __restrict__ delta,   // [B*T][R]
    const float* __restrict__ dt_w,    // [M][R]
    const float* __restrict__ dt_b,    // [M]
    float* __restrict__ dt_out)        // [B*T][M]
{
  __shared__ float ds_d[R_][68];
  __shared__ float ds_w[R_][68];
  const int tid = threadIdx.x;
  const int m0  = blockIdx.x * 64;
  const int bt0 = blockIdx.y * 64;

  #pragma unroll
  for (int k = 0; k < 4; ++k) {
    int idx = tid + k * 256;
    int rq = idx & 15;
    int x  = idx >> 4;
    float4 dv = *reinterpret_cast<const float4*>(&delta[(size_t)(bt0 + x) * R_ + rq * 4]);
    ds_d[rq * 4 + 0][x] = dv.x; ds_d[rq * 4 + 1][x] = dv.y;
    ds_d[rq * 4 + 2][x] = dv.z; ds_d[rq * 4 + 3][x] = dv.w;
    float4 wv = *reinterpret_cast<const float4*>(&dt_w[(size_t)(m0 + x) * R_ + rq * 4]);
    ds_w[rq * 4 + 0][x] = wv.x; ds_w[rq * 4 + 1][x] = wv.y;
    ds_w[rq * 4 + 2][x] = wv.z; ds_w[rq * 4 + 3][x] = wv.w;
  }
  __syncthreads();

  const int mq = tid & 15, tq = tid >> 4;
  const int ml = mq * 4, tl = tq * 4;
  float acc[4][4] = {};
  #pragma unroll 4
  for (int r = 0; r < R_; ++r) {
    float4 dv = *reinterpret_cast<const float4*>(&ds_d[r][tl]);
    float4 wv = *reinterpret_cast<const float4*>(&ds_w[r][ml]);
    float d[4] = {dv.x, dv.y, dv.z, dv.w};
    float w[4] = {wv.x, wv.y, wv.z, wv.w};
    #pragma unroll
    for (int i = 0; i < 4; ++i)
      #pragma unroll
      for (int j = 0; j < 4; ++j)
        acc[i][j] = fmaf(d[i], w[j], acc[i][j]);
  }

  float4 bb = *reinterpret_cast<const float4*>(&dt_b[m0 + ml]);
  float bv[4] = {bb.x, bb.y, bb.z, bb.w};
  #pragma unroll
  for (int i = 0; i < 4; ++i) {
    float4 o;
    float* op = &o.x;
    #pragma unroll
    for (int j = 0; j < 4; ++j) {
      float x = acc[i][j] + bv[j];
      float sp = (x > 20.f) ? x : __logf(1.f + __expf(x));   // softplus (HW exp/log)
      op[j] = fminf(fmaxf(sp, 1e-6f), 10.f);
    }
    *reinterpret_cast<float4*>(&dt_out[(size_t)(bt0 + tl + i) * M_ + m0 + ml]) = o;
  }
}

// --------------------------------------------------------------------------
// Kernel 2 (v3): wave-per-bt-row, no LDS. Each lane holds 1/64 of the K=768
// reduction for all 32 s rows; W reads are wave-coalesced 1 KB segments
// (L2-resident, 96 KB total). Butterfly pack-reduce delivers s = lane&31.
// 1024 blocks x 4 waves -> 16 waves/CU.
// --------------------------------------------------------------------------
__global__ __launch_bounds__(256) void bc_kernel(
    const float* __restrict__ u,     // [B*T][M]
    const float* __restrict__ B_w,   // [S][M]
    const float* __restrict__ C_w,   // [S][M]
    float* __restrict__ Bm,          // [B*T][S]
    float* __restrict__ Cm)          // [B*T][S]
{
  const int wave = threadIdx.x >> 6, lane = threadIdx.x & 63;
  const int bt = blockIdx.x * 4 + wave;
  const float4* ur = reinterpret_cast<const float4*>(&u[(size_t)bt * M_]);
  const float4 a0 = ur[lane], a1 = ur[64 + lane], a2 = ur[128 + lane];

  float acc[32];
  #pragma unroll
  for (int s = 0; s < 32; ++s) {
    const float* wr = (s < 16) ? &B_w[(size_t)s * M_] : &C_w[(size_t)(s - 16) * M_];
    const float4* w4 = reinterpret_cast<const float4*>(wr);
    float4 w0 = w4[lane], w1 = w4[64 + lane], w2 = w4[128 + lane];
    float t = 0.f;
    t = fmaf(a0.x, w0.x, t); t = fmaf(a0.y, w0.y, t);
    t = fmaf(a0.z, w0.z, t); t = fmaf(a0.w, w0.w, t);
    t = fmaf(a1.x, w1.x, t); t = fmaf(a1.y, w1.y, t);
    t = fmaf(a1.z, w1.z, t); t = fmaf(a1.w, w1.w, t);
    t = fmaf(a2.x, w2.x, t); t = fmaf(a2.y, w2.y, t);
    t = fmaf(a2.z, w2.z, t); t = fmaf(a2.w, w2.w, t);
    acc[s] = t;
  }

  // fold lanes 32..63 onto 0..31
  #pragma unroll
  for (int j = 0; j < 32; ++j) acc[j] += __shfl_xor(acc[j], 32);
  // pack butterfly: lane i ends with full sum for s = i & 31 in acc[0]
  int cnt = 32;
  #pragma unroll
  for (int mask = 16; mask >= 1; mask >>= 1) {
    cnt >>= 1;
    const bool up = (lane & mask) != 0;
    #pragma unroll
    for (int j = 0; j < cnt; ++j) {
      float give = up ? acc[j] : acc[j + cnt];
      float keep = up ? acc[j + cnt] : acc[j];
      acc[j] = keep + __shfl_xor(give, mask);
    }
  }

  if (lane < 32) {
    const int s = lane;
    if (s < 16) Bm[(size_t)bt * S_ + s] = acc[0];
    else        Cm[(size_t)bt * S_ + (s - 16)] = acc[0];
  }
}

// --------------------------------------------------------------------------
// Kernels 3 & 5: chunk-local scan, s-split. 128-thr blocks; thread owns
// (b, m, chunk, s-half) with 8 s-states in registers. Lane bit 5 selects the
// s-half; phase-3 y is combined with one shfl_xor(32). Summary layout
// [B][NC][S][M] so every summary access is per-m coalesced.
// --------------------------------------------------------------------------
template <int PHASE, int NCt>
__global__ __launch_bounds__(128) void scan_kernel(
    const float* __restrict__ dt_ws,   // [B*T][M]
    const float* __restrict__ u,       // [B*T][M]
    const float* __restrict__ Bm,      // [B*T][S]
    const float* __restrict__ Cm,      // [B*T][S]
    const float* __restrict__ A_log,   // [S][M]
    const float* __restrict__ D,       // [M]
    float* __restrict__ Aprod,         // [B][NCt][S][M]
    float* __restrict__ Hend,          // [B][NCt][S][M]
    const float* __restrict__ carry,   // [B][NCt][S][M]
    float* __restrict__ out)           // [B*T][M]
{
  constexpr int CL = T_ / NCt;
  __shared__ float lds_bm[CL * S_];
  __shared__ float lds_cm[CL * S_];
  const int tid = threadIdx.x;
  const int ln = tid & 63;
  const int wv = tid >> 6;
  const int shalf = ln >> 5;
  const int s0 = shalf * 8;
  const int m = blockIdx.x * 64 + wv * 32 + (ln & 31);
  const int c = blockIdx.y, b = blockIdx.z;
  const int t0 = c * CL;

  {
    const size_t bcb = ((size_t)b * T_ + t0) * S_;
    for (int idx = tid; idx < CL * S_; idx += 128) {
      lds_bm[idx] = Bm[bcb + idx];
      if constexpr (PHASE == 3) lds_cm[idx] = Cm[bcb + idx];
    }
  }
  __syncthreads();

  float Acol[8];
  #pragma unroll
  for (int s = 0; s < 8; ++s) {
    float a = -__expf(A_log[(size_t)(s0 + s) * M_ + m]);
    Acol[s] = fminf(fmaxf(a, -10.f), -1e-6f);
  }

  float h[8], P[8], Dm = 0.f;
  const size_t smb = (((size_t)b * NCt + c) * S_ + s0) * M_ + m;
  if constexpr (PHASE == 1) {
    #pragma unroll
    for (int s = 0; s < 8; ++s) { h[s] = 0.f; P[s] = 1.f; }
  } else {
    #pragma unroll
    for (int s = 0; s < 8; ++s) h[s] = carry[smb + (size_t)s * M_];
    Dm = D[m];
  }

  const size_t g0 = ((size_t)b * T_ + t0) * M_ + m;
  #pragma unroll
  for (int ti = 0; ti < CL / 8; ++ti) {
    float dt8[8], u8[8];
    #pragma unroll
    for (int k = 0; k < 8; ++k) {
      const size_t gi = g0 + (size_t)(ti * 8 + k) * M_;
      dt8[k] = dt_ws[gi];
      u8[k]  = u[gi];
    }
    #pragma unroll
    for (int k = 0; k < 8; ++k) {
      const int tl = ti * 8 + k;
      const float dtv = dt8[k], uv = u8[k];
      const float du = dtv * uv;
      float y = 0.f;
      #pragma unroll
      for (int s = 0; s < 8; ++s) {
        float la = fmaxf(dtv * Acol[s], LOG_EPS_F);
        float e = __expf(la);
        h[s] = fmaf(e, h[s], du * lds_bm[tl * S_ + s0 + s]);
        if constexpr (PHASE == 1) P[s] *= e;
        else y = fmaf(h[s], lds_cm[tl * S_ + s0 + s], y);
      }
      if constexpr (PHASE == 3) {
        y += __shfl_xor(y, 32);
        if (shalf == 0) {
          float o = y + uv * Dm;
          out[g0 + (size_t)tl * M_] = fminf(fmaxf(o, -1e4f), 1e4f);
        }
      }
    }
  }

  if constexpr (PHASE == 1) {
    #pragma unroll
    for (int s = 0; s < 8; ++s) {
      Aprod[smb + (size_t)s * M_] = P[s];
      Hend[smb + (size_t)s * M_]  = h[s];
    }
  }
}

// --------------------------------------------------------------------------
// Kernel 4: combine chunk summaries into per-chunk input carries.
// Thread = (b, sm) flat; coalesced; unroll pipelines loads ahead of the chain.
// --------------------------------------------------------------------------
template <int NCt>
__global__ __launch_bounds__(256) void carry_kernel(
    const float* __restrict__ Aprod, const float* __restrict__ Hend,
    float* __restrict__ carry)
{
  const int idx = blockIdx.x * 256 + threadIdx.x;  // over B*S*M
  const int b = idx / MS_;
  const int sm = idx - b * MS_;
  float h = 0.f;
  #pragma unroll 16
  for (int c = 0; c < NCt; ++c) {
    const size_t o = ((size_t)b * NCt + c) * MS_ + sm;
    carry[o] = h;
    h = fmaf(Aprod[o], h, Hend[o]);
  }
}

// --------------------------------------------------------------------------
extern "C" void kernel_launch(void* const* d_in, const int* in_sizes, int n_in,
                              void* d_out, int out_size, void* d_ws, size_t ws_size,
                              hipStream_t stream)
{
  const float* u     = (const float*)d_in[0];
  const float* delta = (const float*)d_in[1];
  const float* dt_w  = (const float*)d_in[2];
  const float* dt_b  = (const float*)d_in[3];
  const float* A_log = (const float*)d_in[4];
  const float* B_w   = (const float*)d_in[5];
  const float* C_w   = (const float*)d_in[6];
  const float* D     = (const float*)d_in[7];
  float* out = (float*)d_out;
  float* ws  = (float*)d_ws;

  const size_t fl_dt = (size_t)B_ * T_ * M_;
  const size_t fl_bc = (size_t)B_ * T_ * S_;

  const size_t sum128 = (size_t)B_ * 128 * MS_;
  const size_t need128 = (fl_dt + 2 * fl_bc + 3 * sum128) * sizeof(float);
  const bool big = ws_size >= need128;

  float* dt_ws = ws;
  float* Bm    = dt_ws + fl_dt;
  float* Cm    = Bm + fl_bc;
  float* Aprod = Cm + fl_bc;

  dt_kernel<<<dim3(M_ / 64, (B_ * T_) / 64), 256, 0, stream>>>(delta, dt_w, dt_b, dt_ws);
  bc_kernel<<<dim3((B_ * T_) / 4), 256, 0, stream>>>(u, B_w, C_w, Bm, Cm);

  if (big) {
    constexpr int NCt = 128;
    const size_t sumN = (size_t)B_ * NCt * MS_;
    float* Hend  = Aprod + sumN;
    float* carry = Hend + sumN;
    scan_kernel<1, NCt><<<dim3(M_ / 64, NCt, B_), 128, 0, stream>>>(
        dt_ws, u, Bm, Cm, A_log, D, Aprod, Hend, nullptr, nullptr);
    carry_kernel<NCt><<<dim3((B_ * MS_) / 256), 256, 0, stream>>>(Aprod, Hend, carry);
    scan_kernel<3, NCt><<<dim3(M_ / 64, NCt, B_), 128, 0, stream>>>(
        dt_ws, u, Bm, Cm, A_log, D, Aprod, Hend, carry, out);
  } else {
    constexpr int NCt = 64;
    const size_t sumN = (size_t)B_ * NCt * MS_;
    float* Hend  = Aprod + sumN;
    float* carry = Hend + sumN;
    scan_kernel<1, NCt><<<dim3(M_ / 64, NCt, B_), 128, 0, stream>>>(
        dt_ws, u, Bm, Cm, A_log, D, Aprod, Hend, nullptr, nullptr);
    carry_kernel<NCt><<<dim3((B_ * MS_) / 256), 256, 0, stream>>>(Aprod, Hend, carry);
    scan_kernel<3, NCt><<<dim3(M_ / 64, NCt, B_), 128, 0, stream>>>(
        dt_ws, u, Bm, Cm, A_log, D, Aprod, Hend, carry, out);
  }
}

// Round 4
// 99.735 us; speedup vs baseline: 1.4030x; 1.2623x over previous
//
#include <hip/hip_runtime.h>
#include <math.h>

// Problem constants (match reference)
#define B_ 2
#define T_ 2048
#define M_ 768
#define R_ 64
#define S_ 16
#define MS_ (M_ * S_)
#define NC 64
#define CL 32              // T_ / NC
#define LOG_EPS_F (-23.025850929940457f)

// --------------------------------------------------------------------------
// Kernel 1: dt[bt][m] = clip(softplus(delta[bt][:] . dt_w[m][:] + dt_b[m]))
// Tiled 64x64 GEMM-like, K=64, LDS-staged with transpose.
// --------------------------------------------------------------------------
__global__ __launch_bounds__(256) void dt_kernel(
    const float* __restrict__ delta,   // [B*T][R]
    const float* __restrict__ dt_w,    // [M][R]
    const float* __restrict__ dt_b,    // [M]
    float* __restrict__ dt_out)        // [B*T][M]
{
  __shared__ float ds_d[R_][68];
  __shared__ float ds_w[R_][68];
  const int tid = threadIdx.x;
  const int m0  = blockIdx.x * 64;
  const int bt0 = blockIdx.y * 64;

  #pragma unroll
  for (int k = 0; k < 4; ++k) {
    int idx = tid + k * 256;
    int rq = idx & 15;
    int x  = idx >> 4;
    float4 dv = *reinterpret_cast<const float4*>(&delta[(size_t)(bt0 + x) * R_ + rq * 4]);
    ds_d[rq * 4 + 0][x] = dv.x; ds_d[rq * 4 + 1][x] = dv.y;
    ds_d[rq * 4 + 2][x] = dv.z; ds_d[rq * 4 + 3][x] = dv.w;
    float4 wv = *reinterpret_cast<const float4*>(&dt_w[(size_t)(m0 + x) * R_ + rq * 4]);
    ds_w[rq * 4 + 0][x] = wv.x; ds_w[rq * 4 + 1][x] = wv.y;
    ds_w[rq * 4 + 2][x] = wv.z; ds_w[rq * 4 + 3][x] = wv.w;
  }
  __syncthreads();

  const int mq = tid & 15, tq = tid >> 4;
  const int ml = mq * 4, tl = tq * 4;
  float acc[4][4] = {};
  #pragma unroll 4
  for (int r = 0; r < R_; ++r) {
    float4 dv = *reinterpret_cast<const float4*>(&ds_d[r][tl]);
    float4 wv = *reinterpret_cast<const float4*>(&ds_w[r][ml]);
    float d[4] = {dv.x, dv.y, dv.z, dv.w};
    float w[4] = {wv.x, wv.y, wv.z, wv.w};
    #pragma unroll
    for (int i = 0; i < 4; ++i)
      #pragma unroll
      for (int j = 0; j < 4; ++j)
        acc[i][j] = fmaf(d[i], w[j], acc[i][j]);
  }

  float4 bb = *reinterpret_cast<const float4*>(&dt_b[m0 + ml]);
  float bv[4] = {bb.x, bb.y, bb.z, bb.w};
  #pragma unroll
  for (int i = 0; i < 4; ++i) {
    float4 o;
    float* op = &o.x;
    #pragma unroll
    for (int j = 0; j < 4; ++j) {
      float x = acc[i][j] + bv[j];
      float sp = (x > 20.f) ? x : __logf(1.f + __expf(x));
      op[j] = fminf(fmaxf(sp, 1e-6f), 10.f);
    }
    *reinterpret_cast<float4*>(&dt_out[(size_t)(bt0 + tl + i) * M_ + m0 + ml]) = o;
  }
}

// --------------------------------------------------------------------------
// Kernel 2 (v5): register-cached W. Wave holds a K-slice of 8 s-rows of W in
// VGPRs (96 regs) and processes 8 bt rows -> W traffic 393 MB -> 48 MB.
// 4 waves/block cover 32 s; reduce via verified fold+pack butterfly, 63 shfl
// per 4 rows. Grid 512 blocks x 256 thr.
// --------------------------------------------------------------------------
__global__ __launch_bounds__(256) void bc_kernel(
    const float* __restrict__ u,     // [B*T][M]
    const float* __restrict__ B_w,   // [S][M]
    const float* __restrict__ C_w,   // [S][M]
    float* __restrict__ Bm,          // [B*T][S]
    float* __restrict__ Cm)          // [B*T][S]
{
  const int wave = threadIdx.x >> 6, lane = threadIdx.x & 63;
  const int bt0 = blockIdx.x * 8;

  // W slice for this wave's 8 s rows: w[s][j] = row[j*64 + lane] (float4)
  float4 w[8][3];
  #pragma unroll
  for (int s = 0; s < 8; ++s) {
    const int s_g = wave * 8 + s;
    const float* wr = (s_g < 16) ? &B_w[(size_t)s_g * M_] : &C_w[(size_t)(s_g - 16) * M_];
    const float4* w4 = reinterpret_cast<const float4*>(wr);
    w[s][0] = w4[lane]; w[s][1] = w4[64 + lane]; w[s][2] = w4[128 + lane];
  }

  #pragma unroll
  for (int half = 0; half < 2; ++half) {
    float acc[32];
    #pragma unroll
    for (int r = 0; r < 4; ++r) {
      const int bt = bt0 + half * 4 + r;
      const float4* ur = reinterpret_cast<const float4*>(&u[(size_t)bt * M_]);
      const float4 a0 = ur[lane], a1 = ur[64 + lane], a2 = ur[128 + lane];
      #pragma unroll
      for (int s = 0; s < 8; ++s) {
        float t = 0.f;
        t = fmaf(a0.x, w[s][0].x, t); t = fmaf(a0.y, w[s][0].y, t);
        t = fmaf(a0.z, w[s][0].z, t); t = fmaf(a0.w, w[s][0].w, t);
        t = fmaf(a1.x, w[s][1].x, t); t = fmaf(a1.y, w[s][1].y, t);
        t = fmaf(a1.z, w[s][1].z, t); t = fmaf(a1.w, w[s][1].w, t);
        t = fmaf(a2.x, w[s][2].x, t); t = fmaf(a2.y, w[s][2].y, t);
        t = fmaf(a2.z, w[s][2].z, t); t = fmaf(a2.w, w[s][2].w, t);
        acc[r * 8 + s] = t;
      }
    }

    // fold lanes 32..63 onto 0..31, then pack butterfly over bits 4..0:
    // lane l ends with full sum for index l&31 (= r*8+s) in acc[0].
    #pragma unroll
    for (int j = 0; j < 32; ++j) acc[j] += __shfl_xor(acc[j], 32);
    int cnt = 32;
    #pragma unroll
    for (int mask = 16; mask >= 1; mask >>= 1) {
      cnt >>= 1;
      const bool up = (lane & mask) != 0;
      #pragma unroll
      for (int j = 0; j < cnt; ++j) {
        float give = up ? acc[j] : acc[j + cnt];
        float keep = up ? acc[j + cnt] : acc[j];
        acc[j] = keep + __shfl_xor(give, mask);
      }
    }

    if (lane < 32) {
      const int r = lane >> 3, s_l = lane & 7;
      const int bt = bt0 + half * 4 + r;
      const int s_g = wave * 8 + s_l;
      if (s_g < 16) Bm[(size_t)bt * S_ + s_g] = acc[0];
      else          Cm[(size_t)bt * S_ + (s_g - 16)] = acc[0];
    }
  }
}

// --------------------------------------------------------------------------
// Kernels 3 & 5 (v4): chunk-local scan with LDS-staged dt/u. Block = 128 thr
// (2 waves) covering 64 m x 2 s-halves. Chunk's dt/u staged once (coalesced),
// recurrence reads LDS only. Summaries [B][NC][S][M] coalesced per m.
// --------------------------------------------------------------------------
template <int PHASE>
__global__ __launch_bounds__(128) void scan_kernel(
    const float* __restrict__ dt_ws,   // [B*T][M]
    const float* __restrict__ u,       // [B*T][M]
    const float* __restrict__ Bm,      // [B*T][S]
    const float* __restrict__ Cm,      // [B*T][S]
    const float* __restrict__ A_log,   // [S][M]
    const float* __restrict__ D,       // [M]
    float* __restrict__ Aprod,         // [B][NC][S][M]; carry after kernel 4
    float* __restrict__ Hend,          // [B][NC][S][M]
    float* __restrict__ out)           // [B*T][M]
{
  __shared__ float dt_lds[CL][64];
  __shared__ float u_lds[CL][64];
  __shared__ float lds_bm[CL * S_];
  __shared__ float lds_cm[CL * S_];

  const int tid = threadIdx.x;
  const int lane = tid & 63, wv = tid >> 6;
  const int m_l = wv * 32 + (lane & 31);     // 0..63
  const int sh = lane >> 5, s0 = sh * 8;
  const int m = blockIdx.x * 64 + m_l;
  const int c = blockIdx.y, b = blockIdx.z;
  const int t0 = c * CL;

  // stage dt/u chunk: [32 t][64 m] each, coalesced float4
  const size_t gbase = ((size_t)b * T_ + t0) * M_ + blockIdx.x * 64;
  #pragma unroll
  for (int p = 0; p < 4; ++p) {
    const int i4 = tid + p * 128;
    const int t = i4 >> 4, m4 = (i4 & 15) * 4;
    *reinterpret_cast<float4*>(&dt_lds[t][m4]) =
        *reinterpret_cast<const float4*>(&dt_ws[gbase + (size_t)t * M_ + m4]);
    *reinterpret_cast<float4*>(&u_lds[t][m4]) =
        *reinterpret_cast<const float4*>(&u[gbase + (size_t)t * M_ + m4]);
  }
  {
    const size_t bcb = ((size_t)b * T_ + t0) * S_;
    #pragma unroll
    for (int p = 0; p < 4; ++p) {
      const int idx = tid + p * 128;
      lds_bm[idx] = Bm[bcb + idx];
      if constexpr (PHASE == 3) lds_cm[idx] = Cm[bcb + idx];
    }
  }

  float Acol[8];
  #pragma unroll
  for (int s = 0; s < 8; ++s) {
    float a = -__expf(A_log[(size_t)(s0 + s) * M_ + m]);
    Acol[s] = fminf(fmaxf(a, -10.f), -1e-6f);
  }

  float h[8], P[8], Dm = 0.f;
  const size_t smb = (((size_t)b * NC + c) * S_ + s0) * M_ + m;
  if constexpr (PHASE == 1) {
    #pragma unroll
    for (int s = 0; s < 8; ++s) { h[s] = 0.f; P[s] = 1.f; }
  } else {
    #pragma unroll
    for (int s = 0; s < 8; ++s) h[s] = Aprod[smb + (size_t)s * M_];  // carry
    Dm = D[m];
  }

  __syncthreads();

  const size_t g0 = ((size_t)b * T_ + t0) * M_ + m;
  #pragma unroll 8
  for (int t = 0; t < CL; ++t) {
    const float dtv = dt_lds[t][m_l];
    const float uv  = u_lds[t][m_l];
    const float du  = dtv * uv;
    const float4 bv0 = *reinterpret_cast<const float4*>(&lds_bm[t * S_ + s0]);
    const float4 bv1 = *reinterpret_cast<const float4*>(&lds_bm[t * S_ + s0 + 4]);
    const float bmv[8] = {bv0.x, bv0.y, bv0.z, bv0.w, bv1.x, bv1.y, bv1.z, bv1.w};
    float cmv[8];
    if constexpr (PHASE == 3) {
      const float4 cv0 = *reinterpret_cast<const float4*>(&lds_cm[t * S_ + s0]);
      const float4 cv1 = *reinterpret_cast<const float4*>(&lds_cm[t * S_ + s0 + 4]);
      cmv[0] = cv0.x; cmv[1] = cv0.y; cmv[2] = cv0.z; cmv[3] = cv0.w;
      cmv[4] = cv1.x; cmv[5] = cv1.y; cmv[6] = cv1.z; cmv[7] = cv1.w;
    }
    float y = 0.f;
    #pragma unroll
    for (int s = 0; s < 8; ++s) {
      float la = fmaxf(dtv * Acol[s], LOG_EPS_F);
      float e = __expf(la);
      h[s] = fmaf(e, h[s], du * bmv[s]);
      if constexpr (PHASE == 1) P[s] *= e;
      else y = fmaf(h[s], cmv[s], y);
    }
    if constexpr (PHASE == 3) {
      y += __shfl_xor(y, 32);
      if (sh == 0) {
        float o = y + uv * Dm;
        out[g0 + (size_t)t * M_] = fminf(fmaxf(o, -1e4f), 1e4f);
      }
    }
  }

  if constexpr (PHASE == 1) {
    #pragma unroll
    for (int s = 0; s < 8; ++s) {
      Aprod[smb + (size_t)s * M_] = P[s];
      Hend[smb + (size_t)s * M_]  = h[s];
    }
  }
}

// --------------------------------------------------------------------------
// Kernel 4: chunk-carry combine, in place: Aprod[c] is read (decay product)
// then overwritten with the carry (h-state entering chunk c).
// --------------------------------------------------------------------------
__global__ __launch_bounds__(256) void carry_kernel(
    float* __restrict__ Aprod, const float* __restrict__ Hend)
{
  const int idx = blockIdx.x * 256 + threadIdx.x;  // over B*S*M
  const int b = idx / MS_;
  const int sm = idx - b * MS_;
  float h = 0.f;
  #pragma unroll 16
  for (int c = 0; c < NC; ++c) {
    const size_t o = ((size_t)b * NC + c) * MS_ + sm;
    const float a  = Aprod[o];
    const float he = Hend[o];
    Aprod[o] = h;                 // carry into chunk c
    h = fmaf(a, h, he);
  }
}

// --------------------------------------------------------------------------
extern "C" void kernel_launch(void* const* d_in, const int* in_sizes, int n_in,
                              void* d_out, int out_size, void* d_ws, size_t ws_size,
                              hipStream_t stream)
{
  const float* u     = (const float*)d_in[0];
  const float* delta = (const float*)d_in[1];
  const float* dt_w  = (const float*)d_in[2];
  const float* dt_b  = (const float*)d_in[3];
  const float* A_log = (const float*)d_in[4];
  const float* B_w   = (const float*)d_in[5];
  const float* C_w   = (const float*)d_in[6];
  const float* D     = (const float*)d_in[7];
  float* out = (float*)d_out;
  float* ws  = (float*)d_ws;

  const size_t fl_dt = (size_t)B_ * T_ * M_;   // 3,145,728
  const size_t fl_bc = (size_t)B_ * T_ * S_;   // 65,536
  const size_t fl_sm = (size_t)B_ * NC * MS_;  // 1,572,864

  float* dt_ws = ws;                 // dt
  float* Bm    = dt_ws + fl_dt;
  float* Cm    = Bm + fl_bc;
  float* Aprod = Cm + fl_bc;         // later holds carries
  float* Hend  = Aprod + fl_sm;      // total 25.7 MB

  dt_kernel<<<dim3(M_ / 64, (B_ * T_) / 64), 256, 0, stream>>>(delta, dt_w, dt_b, dt_ws);
  bc_kernel<<<dim3((B_ * T_) / 8), 256, 0, stream>>>(u, B_w, C_w, Bm, Cm);
  scan_kernel<1><<<dim3(M_ / 64, NC, B_), 128, 0, stream>>>(
      dt_ws, u, Bm, Cm, A_log, D, Aprod, Hend, nullptr);
  carry_kernel<<<dim3((B_ * MS_) / 256), 256, 0, stream>>>(Aprod, Hend);
  scan_kernel<3><<<dim3(M_ / 64, NC, B_), 128, 0, stream>>>(
      dt_ws, u, Bm, Cm, A_log, D, Aprod, Hend, out);
}

// Round 5
// 70.323 us; speedup vs baseline: 1.9898x; 1.4182x over previous
//
#include <hip/hip_runtime.h>
#include <math.h>

// Problem constants (match reference)
#define B_ 2
#define T_ 2048
#define M_ 768
#define R_ 64
#define S_ 16
#define MS_ (M_ * S_)
#define NC 128
#define CL (T_ / NC)       // 16
#define LOG_EPS_F (-23.025850929940457f)

// --------------------------------------------------------------------------
// Kernel 1: dt[bt][m] = clip(softplus(delta[bt][:] . dt_w[m][:] + dt_b[m]))
// Tiled 64x64 GEMM-like, K=64, LDS-staged with transpose.
// --------------------------------------------------------------------------
__global__ __launch_bounds__(256) void dt_kernel(
    const float* __restrict__ delta,   // [B*T][R]
    const float* __restrict__ dt_w,    // [M][R]
    const float* __restrict__ dt_b,    // [M]
    float* __restrict__ dt_out)        // [B*T][M]
{
  __shared__ float ds_d[R_][68];
  __shared__ float ds_w[R_][68];
  const int tid = threadIdx.x;
  const int m0  = blockIdx.x * 64;
  const int bt0 = blockIdx.y * 64;

  #pragma unroll
  for (int k = 0; k < 4; ++k) {
    int idx = tid + k * 256;
    int rq = idx & 15;
    int x  = idx >> 4;
    float4 dv = *reinterpret_cast<const float4*>(&delta[(size_t)(bt0 + x) * R_ + rq * 4]);
    ds_d[rq * 4 + 0][x] = dv.x; ds_d[rq * 4 + 1][x] = dv.y;
    ds_d[rq * 4 + 2][x] = dv.z; ds_d[rq * 4 + 3][x] = dv.w;
    float4 wv = *reinterpret_cast<const float4*>(&dt_w[(size_t)(m0 + x) * R_ + rq * 4]);
    ds_w[rq * 4 + 0][x] = wv.x; ds_w[rq * 4 + 1][x] = wv.y;
    ds_w[rq * 4 + 2][x] = wv.z; ds_w[rq * 4 + 3][x] = wv.w;
  }
  __syncthreads();

  const int mq = tid & 15, tq = tid >> 4;
  const int ml = mq * 4, tl = tq * 4;
  float acc[4][4] = {};
  #pragma unroll 4
  for (int r = 0; r < R_; ++r) {
    float4 dv = *reinterpret_cast<const float4*>(&ds_d[r][tl]);
    float4 wv = *reinterpret_cast<const float4*>(&ds_w[r][ml]);
    float d[4] = {dv.x, dv.y, dv.z, dv.w};
    float w[4] = {wv.x, wv.y, wv.z, wv.w};
    #pragma unroll
    for (int i = 0; i < 4; ++i)
      #pragma unroll
      for (int j = 0; j < 4; ++j)
        acc[i][j] = fmaf(d[i], w[j], acc[i][j]);
  }

  float4 bb = *reinterpret_cast<const float4*>(&dt_b[m0 + ml]);
  float bv[4] = {bb.x, bb.y, bb.z, bb.w};
  #pragma unroll
  for (int i = 0; i < 4; ++i) {
    float4 o;
    float* op = &o.x;
    #pragma unroll
    for (int j = 0; j < 4; ++j) {
      float x = acc[i][j] + bv[j];
      float sp = (x > 20.f) ? x : __logf(1.f + __expf(x));
      op[j] = fminf(fmaxf(sp, 1e-6f), 10.f);
    }
    *reinterpret_cast<float4*>(&dt_out[(size_t)(bt0 + tl + i) * M_ + m0 + ml]) = o;
  }
}

// --------------------------------------------------------------------------
// Kernel 2 (v6): register-cached W, sized to avoid spills. Wave holds 4
// s-rows of W (48 VGPR) and processes 8 bt rows (acc[32] = 8 rows x 4 s).
// Block = 512 thr / 8 waves covering all 32 s. Live set ~105 VGPR < 128.
// Butterfly fold+pack delivers index lane&31 = r*4+s in acc[0].
// --------------------------------------------------------------------------
__global__ __launch_bounds__(512, 4) void bc_kernel(
    const float* __restrict__ u,     // [B*T][M]
    const float* __restrict__ B_w,   // [S][M]
    const float* __restrict__ C_w,   // [S][M]
    float* __restrict__ Bm,          // [B*T][S]
    float* __restrict__ Cm)          // [B*T][S]
{
  const int wave = threadIdx.x >> 6, lane = threadIdx.x & 63;
  const int bt0 = blockIdx.x * 8;

  // W slice for this wave's 4 s rows
  float4 w[4][3];
  #pragma unroll
  for (int s = 0; s < 4; ++s) {
    const int s_g = wave * 4 + s;
    const float* wr = (s_g < 16) ? &B_w[(size_t)s_g * M_] : &C_w[(size_t)(s_g - 16) * M_];
    const float4* w4 = reinterpret_cast<const float4*>(wr);
    w[s][0] = w4[lane]; w[s][1] = w4[64 + lane]; w[s][2] = w4[128 + lane];
  }

  float acc[32];
  #pragma unroll
  for (int r = 0; r < 8; ++r) {
    const float4* ur = reinterpret_cast<const float4*>(&u[(size_t)(bt0 + r) * M_]);
    const float4 a0 = ur[lane], a1 = ur[64 + lane], a2 = ur[128 + lane];
    #pragma unroll
    for (int s = 0; s < 4; ++s) {
      float t = 0.f;
      t = fmaf(a0.x, w[s][0].x, t); t = fmaf(a0.y, w[s][0].y, t);
      t = fmaf(a0.z, w[s][0].z, t); t = fmaf(a0.w, w[s][0].w, t);
      t = fmaf(a1.x, w[s][1].x, t); t = fmaf(a1.y, w[s][1].y, t);
      t = fmaf(a1.z, w[s][1].z, t); t = fmaf(a1.w, w[s][1].w, t);
      t = fmaf(a2.x, w[s][2].x, t); t = fmaf(a2.y, w[s][2].y, t);
      t = fmaf(a2.z, w[s][2].z, t); t = fmaf(a2.w, w[s][2].w, t);
      acc[r * 4 + s] = t;
    }
  }

  // fold lanes 32..63 onto 0..31, then pack butterfly over bits 4..0:
  // lane l ends with full sum for index l&31 in acc[0].
  #pragma unroll
  for (int j = 0; j < 32; ++j) acc[j] += __shfl_xor(acc[j], 32);
  int cnt = 32;
  #pragma unroll
  for (int mask = 16; mask >= 1; mask >>= 1) {
    cnt >>= 1;
    const bool up = (lane & mask) != 0;
    #pragma unroll
    for (int j = 0; j < cnt; ++j) {
      float give = up ? acc[j] : acc[j + cnt];
      float keep = up ? acc[j + cnt] : acc[j];
      acc[j] = keep + __shfl_xor(give, mask);
    }
  }

  if (lane < 32) {
    const int r = lane >> 2, s_l = lane & 3;
    const int s_g = wave * 4 + s_l;
    const int bt = bt0 + r;
    if (s_g < 16) Bm[(size_t)bt * S_ + s_g] = acc[0];
    else          Cm[(size_t)bt * S_ + (s_g - 16)] = acc[0];
  }
}

// --------------------------------------------------------------------------
// Kernels 3 & 5: chunk-local scan with LDS-staged dt/u. Block = 128 thr
// (2 waves) covering 64 m x 2 s-halves. NC=128 chunks (CL=16).
// Summaries [B][NC][S][M] coalesced per m. Aprod doubles as carry buffer.
// --------------------------------------------------------------------------
template <int PHASE>
__global__ __launch_bounds__(128) void scan_kernel(
    const float* __restrict__ dt_ws,   // [B*T][M]
    const float* __restrict__ u,       // [B*T][M]
    const float* __restrict__ Bm,      // [B*T][S]
    const float* __restrict__ Cm,      // [B*T][S]
    const float* __restrict__ A_log,   // [S][M]
    const float* __restrict__ D,       // [M]
    float* __restrict__ Aprod,         // [B][NC][S][M]; carry after kernel 4
    float* __restrict__ Hend,          // [B][NC][S][M]
    float* __restrict__ out)           // [B*T][M]
{
  __shared__ float dt_lds[CL][64];
  __shared__ float u_lds[CL][64];
  __shared__ float lds_bm[CL * S_];
  __shared__ float lds_cm[CL * S_];

  const int tid = threadIdx.x;
  const int lane = tid & 63, wv = tid >> 6;
  const int m_l = wv * 32 + (lane & 31);     // 0..63
  const int sh = lane >> 5, s0 = sh * 8;
  const int m = blockIdx.x * 64 + m_l;
  const int c = blockIdx.y, b = blockIdx.z;
  const int t0 = c * CL;

  // stage dt/u chunk: [CL t][64 m] each, coalesced float4
  const size_t gbase = ((size_t)b * T_ + t0) * M_ + blockIdx.x * 64;
  #pragma unroll
  for (int p = 0; p < CL * 16 / 128; ++p) {
    const int i4 = tid + p * 128;
    const int t = i4 >> 4, m4 = (i4 & 15) * 4;
    *reinterpret_cast<float4*>(&dt_lds[t][m4]) =
        *reinterpret_cast<const float4*>(&dt_ws[gbase + (size_t)t * M_ + m4]);
    *reinterpret_cast<float4*>(&u_lds[t][m4]) =
        *reinterpret_cast<const float4*>(&u[gbase + (size_t)t * M_ + m4]);
  }
  {
    const size_t bcb = ((size_t)b * T_ + t0) * S_;
    #pragma unroll
    for (int p = 0; p < CL * S_ / 128; ++p) {
      const int idx = tid + p * 128;
      lds_bm[idx] = Bm[bcb + idx];
      if constexpr (PHASE == 3) lds_cm[idx] = Cm[bcb + idx];
    }
  }

  float Acol[8];
  #pragma unroll
  for (int s = 0; s < 8; ++s) {
    float a = -__expf(A_log[(size_t)(s0 + s) * M_ + m]);
    Acol[s] = fminf(fmaxf(a, -10.f), -1e-6f);
  }

  float h[8], P[8], Dm = 0.f;
  const size_t smb = (((size_t)b * NC + c) * S_ + s0) * M_ + m;
  if constexpr (PHASE == 1) {
    #pragma unroll
    for (int s = 0; s < 8; ++s) { h[s] = 0.f; P[s] = 1.f; }
  } else {
    #pragma unroll
    for (int s = 0; s < 8; ++s) h[s] = Aprod[smb + (size_t)s * M_];  // carry
    Dm = D[m];
  }

  __syncthreads();

  const size_t g0 = ((size_t)b * T_ + t0) * M_ + m;
  #pragma unroll 8
  for (int t = 0; t < CL; ++t) {
    const float dtv = dt_lds[t][m_l];
    const float uv  = u_lds[t][m_l];
    const float du  = dtv * uv;
    const float4 bv0 = *reinterpret_cast<const float4*>(&lds_bm[t * S_ + s0]);
    const float4 bv1 = *reinterpret_cast<const float4*>(&lds_bm[t * S_ + s0 + 4]);
    const float bmv[8] = {bv0.x, bv0.y, bv0.z, bv0.w, bv1.x, bv1.y, bv1.z, bv1.w};
    float cmv[8];
    if constexpr (PHASE == 3) {
      const float4 cv0 = *reinterpret_cast<const float4*>(&lds_cm[t * S_ + s0]);
      const float4 cv1 = *reinterpret_cast<const float4*>(&lds_cm[t * S_ + s0 + 4]);
      cmv[0] = cv0.x; cmv[1] = cv0.y; cmv[2] = cv0.z; cmv[3] = cv0.w;
      cmv[4] = cv1.x; cmv[5] = cv1.y; cmv[6] = cv1.z; cmv[7] = cv1.w;
    }
    float y = 0.f;
    #pragma unroll
    for (int s = 0; s < 8; ++s) {
      float la = fmaxf(dtv * Acol[s], LOG_EPS_F);
      float e = __expf(la);
      h[s] = fmaf(e, h[s], du * bmv[s]);
      if constexpr (PHASE == 1) P[s] *= e;
      else y = fmaf(h[s], cmv[s], y);
    }
    if constexpr (PHASE == 3) {
      y += __shfl_xor(y, 32);
      if (sh == 0) {
        float o = y + uv * Dm;
        out[g0 + (size_t)t * M_] = fminf(fmaxf(o, -1e4f), 1e4f);
      }
    }
  }

  if constexpr (PHASE == 1) {
    #pragma unroll
    for (int s = 0; s < 8; ++s) {
      Aprod[smb + (size_t)s * M_] = P[s];
      Hend[smb + (size_t)s * M_]  = h[s];
    }
  }
}

// --------------------------------------------------------------------------
// Kernel 4: chunk-carry combine, in place: Aprod[c] is read (decay product)
// then overwritten with the carry (h-state entering chunk c).
// --------------------------------------------------------------------------
__global__ __launch_bounds__(256) void carry_kernel(
    float* __restrict__ Aprod, const float* __restrict__ Hend)
{
  const int idx = blockIdx.x * 256 + threadIdx.x;  // over B*S*M
  const int b = idx / MS_;
  const int sm = idx - b * MS_;
  float h = 0.f;
  #pragma unroll 16
  for (int c = 0; c < NC; ++c) {
    const size_t o = ((size_t)b * NC + c) * MS_ + sm;
    const float a  = Aprod[o];
    const float he = Hend[o];
    Aprod[o] = h;                 // carry into chunk c
    h = fmaf(a, h, he);
  }
}

// --------------------------------------------------------------------------
extern "C" void kernel_launch(void* const* d_in, const int* in_sizes, int n_in,
                              void* d_out, int out_size, void* d_ws, size_t ws_size,
                              hipStream_t stream)
{
  const float* u     = (const float*)d_in[0];
  const float* delta = (const float*)d_in[1];
  const float* dt_w  = (const float*)d_in[2];
  const float* dt_b  = (const float*)d_in[3];
  const float* A_log = (const float*)d_in[4];
  const float* B_w   = (const float*)d_in[5];
  const float* C_w   = (const float*)d_in[6];
  const float* D     = (const float*)d_in[7];
  float* out = (float*)d_out;
  float* ws  = (float*)d_ws;

  const size_t fl_dt = (size_t)B_ * T_ * M_;   // 3,145,728
  const size_t fl_bc = (size_t)B_ * T_ * S_;   // 65,536
  const size_t fl_sm = (size_t)B_ * NC * MS_;  // 3,145,728

  float* dt_ws = ws;
  float* Bm    = dt_ws + fl_dt;
  float* Cm    = Bm + fl_bc;
  float* Aprod = Cm + fl_bc;         // later holds carries
  float* Hend  = Aprod + fl_sm;      // total ~38 MB

  dt_kernel<<<dim3(M_ / 64, (B_ * T_) / 64), 256, 0, stream>>>(delta, dt_w, dt_b, dt_ws);
  bc_kernel<<<dim3((B_ * T_) / 8), 512, 0, stream>>>(u, B_w, C_w, Bm, Cm);
  scan_kernel<1><<<dim3(M_ / 64, NC, B_), 128, 0, stream>>>(
      dt_ws, u, Bm, Cm, A_log, D, Aprod, Hend, nullptr);
  carry_kernel<<<dim3((B_ * MS_) / 256), 256, 0, stream>>>(Aprod, Hend);
  scan_kernel<3><<<dim3(M_ / 64, NC, B_), 128, 0, stream>>>(
      dt_ws, u, Bm, Cm, A_log, D, Aprod, Hend, out);
}